// Round 2
// baseline (420.011 us; speedup 1.0000x reference)
//
#include <hip/hip_runtime.h>
#include <math.h>

// FilterMLPBlock: y = irfft(rfft(x,axis=S,ortho)*w, ortho) ; out = LN_D(y + x)
// B=4096, S=64, D=256, F=33. Spectral filter == per-channel real circulant:
//   h[s,d] = sum_t k'[d][(s-t)&63] * x[t,d],  k'[d][0] = k[d][0] + 1 (residual folded in)
//   k[d][dlt] = (1/64)(wr0 + (-1)^dlt*wr32 + 2*sum_{f=1..31}(wr_f cos - wi_f sin)(2pi f dlt/64))
// (pocketfft c2r drops Im(DC) and Im(Nyquist).)
// Then out = LayerNorm_D(h) * gamma + beta.

#define S_ 64
#define D_ 256
#define LSTR 257   // odd LDS row stride (floats): conflict-free col & row access

__global__ void precompute_k_kernel(const float* __restrict__ cw,
                                    float* __restrict__ k) {
    const int d   = threadIdx.x;   // 0..255
    const int dlt = blockIdx.x;    // 0..63
    // cw layout: [f][d][2] (re, im)
    float acc = cw[(0 * D_ + d) * 2 + 0];                        // wr[0,d]
    acc += ((dlt & 1) ? -1.f : 1.f) * cw[(32 * D_ + d) * 2 + 0]; // wr[32,d]*(-1)^dlt
    const float step = 6.28318530717958647692f / 64.f;
    #pragma unroll
    for (int f = 1; f <= 31; ++f) {
        int m = (f * dlt) & 63;            // exact arg reduction (period 64)
        float th = step * (float)m;
        float sn, cs;
        sincosf(th, &sn, &cs);
        float wr = cw[(f * D_ + d) * 2 + 0];
        float wi = cw[(f * D_ + d) * 2 + 1];
        acc += 2.f * (wr * cs - wi * sn);
    }
    // residual folded in: +1 on the zero-delta tap
    k[dlt * D_ + d] = acc * (1.f / 64.f) + ((dlt == 0) ? 1.f : 0.f);
}

__global__ __launch_bounds__(512, 4)
void filter_ln_kernel(const float* __restrict__ x,
                      const float* __restrict__ k,
                      const float* __restrict__ gamma,
                      const float* __restrict__ beta,
                      float* __restrict__ out) {
    __shared__ float hs[S_ * LSTR];        // h tile for LN reduction
    __shared__ float psum[512];            // 8 partials x 64 rows
    __shared__ float psumsq[512];
    __shared__ float mr[S_ * 2];           // per-row mean, rstd

    const int tid  = threadIdx.x;          // 0..511
    const int d    = tid & 255;            // channel
    const int half = tid >> 8;             // 0 or 1 (wave-uniform)
    const int s0   = half * 32;            // this thread's output-row base
    const int b    = blockIdx.x;
    const float* __restrict__ xb = x + (size_t)b * (S_ * D_);

    // ---- rotated circulant column: kd[i] = k'[(s0+i)&63][d]  (coalesced, L2/L3-hot)
    float kd[64];
    #pragma unroll
    for (int i = 0; i < 64; ++i)
        kd[i] = k[((s0 + i) & 63) * D_ + d];

    // ---- conv: stream x column from global (coalesced, read exactly once per block)
    float y[32];
    #pragma unroll
    for (int s = 0; s < 32; ++s) y[s] = 0.f;
    #pragma unroll
    for (int t = 0; t < 64; ++t) {
        float xt = xb[t * D_ + d];
        #pragma unroll
        for (int s = 0; s < 32; ++s)
            y[s] = fmaf(kd[(s - t) & 63], xt, y[s]);   // static reg indices only
    }

    // ---- write h rows [s0, s0+32) into LDS tile for the LN reduction
    #pragma unroll
    for (int s = 0; s < 32; ++s)
        hs[(s0 + s) * LSTR + d] = y[s];
    __syncthreads();

    // ---- LN stats over D per row (8 partials of 32 elements per row)
    {
        const int s = tid & 63, q = tid >> 6;   // q in 0..7
        float s1 = 0.f, s2 = 0.f;
        #pragma unroll
        for (int j = 0; j < 32; ++j) {
            float v = hs[s * LSTR + q * 32 + j];  // odd stride -> conflict-free
            s1 += v;
            s2 = fmaf(v, v, s2);
        }
        psum[q * 64 + s]   = s1;
        psumsq[q * 64 + s] = s2;
    }
    __syncthreads();
    if (tid < 64) {
        float s1 = 0.f, s2 = 0.f;
        #pragma unroll
        for (int q = 0; q < 8; ++q) {
            s1 += psum[q * 64 + tid];
            s2 += psumsq[q * 64 + tid];
        }
        float mean = s1 * (1.f / 256.f);
        float var  = s2 * (1.f / 256.f) - mean * mean;
        mr[tid * 2 + 0] = mean;
        mr[tid * 2 + 1] = rsqrtf(var + 1e-12f);
    }
    __syncthreads();

    // ---- normalize + affine + coalesced store (h still in registers)
    const float g  = gamma[d];
    const float bt = beta[d];
    float* __restrict__ ob = out + (size_t)b * (S_ * D_);
    #pragma unroll
    for (int s = 0; s < 32; ++s) {
        const int row = s0 + s;
        float m = mr[row * 2 + 0];         // same-address broadcast reads
        float r = mr[row * 2 + 1];
        ob[row * D_ + d] = (y[s] - m) * r * g + bt;
    }
}

extern "C" void kernel_launch(void* const* d_in, const int* in_sizes, int n_in,
                              void* d_out, int out_size, void* d_ws, size_t ws_size,
                              hipStream_t stream) {
    const float* x     = (const float*)d_in[0];
    const float* cw    = (const float*)d_in[1];   // [1,33,256,2]
    const float* gamma = (const float*)d_in[2];
    const float* beta  = (const float*)d_in[3];
    float* out = (float*)d_out;
    float* k   = (float*)d_ws;                    // 64*256*4 = 64 KB scratch

    precompute_k_kernel<<<64, 256, 0, stream>>>(cw, k);
    filter_ln_kernel<<<4096, 512, 0, stream>>>(x, k, gamma, beta, out);
}

// Round 3
// 287.292 us; speedup vs baseline: 1.4620x; 1.4620x over previous
//
#include <hip/hip_runtime.h>
#include <math.h>

// FilterMLPBlock: y = irfft(rfft(x,axis=S,ortho)*w, ortho) ; out = LN_D(y + x)
// B=4096, S=64, D=256, F=33. Spectral filter == per-channel real circulant:
//   h[s,d] = sum_t k'[d][(s-t)&63] * x[t,d],  k'[d][0] = k[d][0] + 1 (residual folded)
//   k[d][dlt] = (1/64)(wr0 + (-1)^dlt*wr32 + 2*sum_{f=1..31}(wr_f cos - wi_f sin)(2pi f dlt/64))
// (pocketfft c2r drops Im(DC) and Im(Nyquist).)  Then out = LN_D(h)*gamma + beta.
//
// R3 design notes:
//  - launch_bounds(256,1): empirically the compiler caps VGPRs at ~256/arg2;
//    arg2=2 (R1) gave 128 regs -> 92-dword spill (385 MB extra HBM writes),
//    arg2=4 (R2) gave 64 regs -> 27-dword spill. Demand is ~180-220 -> arg2=1.
//  - one thread per (b,d) column: kd[64]+y[64] live in regs, all indices static.
//  - x streamed from global, each element read exactly once per block, coalesced.
//  - LDS only for the LN transpose-reduction (stride-257 rows, conflict-free).

#define S_ 64
#define D_ 256
#define LSTR 257   // odd LDS row stride (floats): conflict-free row & col access

__global__ void precompute_k_kernel(const float* __restrict__ cw,
                                    float* __restrict__ k) {
    const int d   = threadIdx.x;   // 0..255
    const int dlt = blockIdx.x;    // 0..63
    // cw layout: [f][d][2] (re, im)
    float acc = cw[(0 * D_ + d) * 2 + 0];                        // wr[0,d]
    acc += ((dlt & 1) ? -1.f : 1.f) * cw[(32 * D_ + d) * 2 + 0]; // wr[32,d]*(-1)^dlt
    const float step = 6.28318530717958647692f / 64.f;
    #pragma unroll
    for (int f = 1; f <= 31; ++f) {
        int m = (f * dlt) & 63;            // exact arg reduction (period 64)
        float th = step * (float)m;
        float sn, cs;
        sincosf(th, &sn, &cs);
        float wr = cw[(f * D_ + d) * 2 + 0];
        float wi = cw[(f * D_ + d) * 2 + 1];
        acc += 2.f * (wr * cs - wi * sn);
    }
    // residual folded in: +1 on the zero-delta tap
    k[dlt * D_ + d] = acc * (1.f / 64.f) + ((dlt == 0) ? 1.f : 0.f);
}

__global__ __launch_bounds__(256, 1)
void filter_ln_kernel(const float* __restrict__ x,
                      const float* __restrict__ k,
                      const float* __restrict__ gamma,
                      const float* __restrict__ beta,
                      float* __restrict__ out) {
    __shared__ float hs[S_ * LSTR];        // h tile for LN reduction (65.8 KB)
    __shared__ float psum[256];            // 4 partials x 64 rows
    __shared__ float psumsq[256];
    __shared__ float mr[S_ * 2];           // per-row mean, rstd

    const int d = threadIdx.x;             // channel 0..255
    const int b = blockIdx.x;
    const float* __restrict__ xb = x + (size_t)b * (S_ * D_);

    // circulant column for this d (coalesced; k is L2/L3-hot, 64 KB total)
    float kd[64];
    #pragma unroll
    for (int dl = 0; dl < 64; ++dl)
        kd[dl] = k[dl * D_ + d];

    // ---- conv: stream own x column from global (coalesced per wave, each
    //      element read exactly once per block). All-register FMAs.
    float y[64];
    #pragma unroll
    for (int s = 0; s < 64; ++s) y[s] = 0.f;
    #pragma unroll
    for (int t = 0; t < 64; ++t) {
        float xt = xb[t * D_ + d];
        #pragma unroll
        for (int s = 0; s < 64; ++s)
            y[s] = fmaf(kd[(s - t) & 63], xt, y[s]);   // static reg indices only
    }

    // ---- write h tile to LDS for the LN transpose-reduction
    #pragma unroll
    for (int s = 0; s < 64; ++s)
        hs[s * LSTR + d] = y[s];
    __syncthreads();

    // ---- LN stats over D per row s (4 partials of 64 elements per row)
    {
        const int s = d & 63, q = d >> 6;   // q in 0..3
        float s1 = 0.f, s2 = 0.f;
        #pragma unroll
        for (int j = 0; j < 64; ++j) {
            float v = hs[s * LSTR + q * 64 + j];  // odd stride -> conflict-free
            s1 += v;
            s2 = fmaf(v, v, s2);
        }
        psum[q * 64 + s]   = s1;
        psumsq[q * 64 + s] = s2;
    }
    __syncthreads();
    if (d < 64) {
        float s1 = psum[d] + psum[64 + d] + psum[128 + d] + psum[192 + d];
        float s2 = psumsq[d] + psumsq[64 + d] + psumsq[128 + d] + psumsq[192 + d];
        float mean = s1 * (1.f / 256.f);
        float var  = s2 * (1.f / 256.f) - mean * mean;
        mr[d * 2 + 0] = mean;
        mr[d * 2 + 1] = rsqrtf(var + 1e-12f);
    }
    __syncthreads();

    // ---- normalize + affine + coalesced store (h still in registers)
    const float g  = gamma[d];
    const float bt = beta[d];
    float* __restrict__ ob = out + (size_t)b * (S_ * D_);
    #pragma unroll
    for (int s = 0; s < 64; ++s) {
        float m = mr[s * 2 + 0];           // same-address broadcast reads
        float r = mr[s * 2 + 1];
        ob[s * D_ + d] = (y[s] - m) * r * g + bt;
    }
}

extern "C" void kernel_launch(void* const* d_in, const int* in_sizes, int n_in,
                              void* d_out, int out_size, void* d_ws, size_t ws_size,
                              hipStream_t stream) {
    const float* x     = (const float*)d_in[0];
    const float* cw    = (const float*)d_in[1];   // [1,33,256,2]
    const float* gamma = (const float*)d_in[2];
    const float* beta  = (const float*)d_in[3];
    float* out = (float*)d_out;
    float* k   = (float*)d_ws;                    // 64*256*4 = 64 KB scratch

    precompute_k_kernel<<<64, 256, 0, stream>>>(cw, k);
    filter_ln_kernel<<<4096, 256, 0, stream>>>(x, k, gamma, beta, out);
}

// Round 4
// 280.631 us; speedup vs baseline: 1.4967x; 1.0237x over previous
//
#include <hip/hip_runtime.h>
#include <math.h>

// FilterMLPBlock: y = irfft(rfft(x,axis=S,ortho)*w, ortho) ; out = LN_D(y + x)
// B=4096, S=64, D=256, F=33. Spectral filter == per-channel real circulant:
//   h[s,d] = sum_t k'[d][(s-t)&63] * x[t,d],  k'[d][0] = k[d][0] + 1 (residual folded)
//   k[d][dlt] = (1/64)(wr0 + (-1)^dlt*wr32 + 2*sum_{f=1..31}(wr_f cos - wi_f sin)(2pi f dlt/64))
// (pocketfft c2r drops Im(DC) and Im(Nyquist).)  Then out = LN_D(h)*gamma + beta.
//
// R4 design notes:
//  - R3 post-mortem: WRITE_SIZE was 2x output == 64 dwords/thread of scratch:
//    the 4096-FMA t-loop didn't fully unroll -> kd[(s-t)&63] runtime-indexed
//    -> kd[64] allocated to scratch (rule: runtime-indexed arrays -> scratch).
//    Fix: macro-expand all 64 steps so every register-array index is a
//    compile-time constant regardless of unroll heuristics.
//  - x is NOT staged anywhere: each x[t,d] is used by exactly one thread,
//    64 times, while held in a single register. Stream from global, coalesced.
//  - LDS holds only the h tile for the LN cross-thread reduction, stored as
//    rn-rounded bf16 [64][258] (33 KB; odd-uint row stride -> conflict-free).
//    h stays fp32 in registers for the final normalize; bf16 only affects
//    mean/var (~0.3% rel), well inside the 0.12 absmax threshold.
//  - launch_bounds(256,3): VGPR cap ~168 vs mandatory kd[64]+y[64]+temps~140
//    -> no spill, 3 blocks/CU (12 waves/CU) with 35.5 KB LDS.

#define S_ 64
#define D_ 256
#define TS 258   // ushort row stride: uint stride 129 (odd) -> conflict-free

#define REP4(M, B)  M(B) M((B)+1) M((B)+2) M((B)+3)
#define REP16(M, B) REP4(M, B) REP4(M, (B)+4) REP4(M, (B)+8) REP4(M, (B)+12)
#define REP64(M)    REP16(M, 0) REP16(M, 16) REP16(M, 32) REP16(M, 48)

__global__ void precompute_k_kernel(const float* __restrict__ cw,
                                    float* __restrict__ k) {
    const int d   = threadIdx.x;   // 0..255
    const int dlt = blockIdx.x;    // 0..63
    // cw layout: [f][d][2] (re, im)
    float acc = cw[(0 * D_ + d) * 2 + 0];                        // wr[0,d]
    acc += ((dlt & 1) ? -1.f : 1.f) * cw[(32 * D_ + d) * 2 + 0]; // wr[32,d]*(-1)^dlt
    const float step = 6.28318530717958647692f / 64.f;
    #pragma unroll
    for (int f = 1; f <= 31; ++f) {
        int m = (f * dlt) & 63;            // exact arg reduction (period 64)
        float th = step * (float)m;
        float sn, cs;
        sincosf(th, &sn, &cs);
        float wr = cw[(f * D_ + d) * 2 + 0];
        float wi = cw[(f * D_ + d) * 2 + 1];
        acc += 2.f * (wr * cs - wi * sn);
    }
    // residual folded in: +1 on the zero-delta tap
    k[dlt * D_ + d] = acc * (1.f / 64.f) + ((dlt == 0) ? 1.f : 0.f);
}

__global__ __launch_bounds__(256, 3)
void filter_ln_kernel(const float* __restrict__ x,
                      const float* __restrict__ k,
                      const float* __restrict__ gamma,
                      const float* __restrict__ beta,
                      float* __restrict__ out) {
    __shared__ unsigned short hs2[S_ * TS];   // h tile (bf16) for LN reduction
    __shared__ float psum[256];               // 4 partials x 64 rows
    __shared__ float psumsq[256];
    __shared__ float mr[S_ * 2];              // per-row mean, rstd

    const int d = threadIdx.x;                // channel 0..255
    const int b = blockIdx.x;
    const float* __restrict__ xb = x + (size_t)b * (S_ * D_);

    // ---- circulant column for this d: every index is a literal constant ----
    float kd[64];
#define KLOAD(I) kd[I] = k[(I) * D_ + d];
    REP64(KLOAD)
#undef KLOAD

    float y[64];
#define YZERO(I) y[I] = 0.f;
    REP64(YZERO)
#undef YZERO

    // ---- conv: stream own x column from global (each element read once,
    //      held in one reg for its 64 uses). All indices compile-time. ----
#define CONV_STEP(T) { const float xt = xb[(T) * D_ + d]; \
    _Pragma("unroll") \
    for (int s = 0; s < 64; ++s) y[s] = fmaf(kd[(s - (T)) & 63], xt, y[s]); }
    REP64(CONV_STEP)
#undef CONV_STEP

    // ---- write h (bf16 rn) into LDS tile for the cross-thread LN stats ----
#define HWRITE(T) { unsigned hb = __float_as_uint(y[T]); \
    hb = hb + 0x7fffu + ((hb >> 16) & 1u); \
    hs2[(T) * TS + d] = (unsigned short)(hb >> 16); }
    REP64(HWRITE)
#undef HWRITE
    __syncthreads();

    // ---- LN stats over D per row s (4 partials of 64 elements per row) ----
    {
        const int s = d & 63, q = d >> 6;     // q in 0..3
        float s1 = 0.f, s2 = 0.f;
        #pragma unroll
        for (int j = 0; j < 64; ++j) {        // scalars only; LDS runtime idx OK
            float v = __uint_as_float((unsigned)hs2[s * TS + q * 64 + j] << 16);
            s1 += v;
            s2 = fmaf(v, v, s2);
        }
        psum[q * 64 + s]   = s1;
        psumsq[q * 64 + s] = s2;
    }
    __syncthreads();
    if (d < 64) {
        float s1 = psum[d] + psum[64 + d] + psum[128 + d] + psum[192 + d];
        float s2 = psumsq[d] + psumsq[64 + d] + psumsq[128 + d] + psumsq[192 + d];
        float mean = s1 * (1.f / 256.f);
        float var  = s2 * (1.f / 256.f) - mean * mean;
        mr[d * 2 + 0] = mean;
        mr[d * 2 + 1] = rsqrtf(var + 1e-12f);
    }
    __syncthreads();

    // ---- normalize fp32 h (still in regs) + affine + coalesced store ----
    const float g  = gamma[d];
    const float bt = beta[d];
    float* __restrict__ ob = out + (size_t)b * (S_ * D_);
#define STORE(T) { const float m = mr[(T) * 2 + 0], r = mr[(T) * 2 + 1]; \
    ob[(T) * D_ + d] = (y[T] - m) * r * g + bt; }
    REP64(STORE)
#undef STORE
}

extern "C" void kernel_launch(void* const* d_in, const int* in_sizes, int n_in,
                              void* d_out, int out_size, void* d_ws, size_t ws_size,
                              hipStream_t stream) {
    const float* x     = (const float*)d_in[0];
    const float* cw    = (const float*)d_in[1];   // [1,33,256,2]
    const float* gamma = (const float*)d_in[2];
    const float* beta  = (const float*)d_in[3];
    float* out = (float*)d_out;
    float* kk  = (float*)d_ws;                    // 64*256*4 = 64 KB scratch

    precompute_k_kernel<<<64, 256, 0, stream>>>(cw, kk);
    filter_ln_kernel<<<4096, 256, 0, stream>>>(x, kk, gamma, beta, out);
}